// Round 7
// baseline (388.267 us; speedup 1.0000x reference)
//
#include <hip/hip_runtime.h>
#include <stdint.h>

using f4v = __attribute__((ext_vector_type(4))) float;
using s8v = __attribute__((ext_vector_type(8))) short;

constexpr int C_ = 128, H_ = 128, W_ = 128, HW_ = H_ * W_;
constexpr int S_ = 4;             // y-splits for k_dw
constexpr int OROWS = H_ / S_;    // 32 output rows per block
constexpr int CHB = 4;            // channels per k_dw block (wave-uniform)
constexpr int TPB = 512;
static_assert(OROWS == 32, "bias table indexing assumes 32 rows/block");

__device__ __forceinline__ unsigned f2bf(float f) {
  union { float f; unsigned u; } v; v.f = f;
  return (v.u + 0x7FFFu + ((v.u >> 16) & 1u)) >> 16;   // RTNE
}

// force a wave-uniform float into an SGPR
__device__ __forceinline__ float sgpr(float v) {
  return __int_as_float(__builtin_amdgcn_readfirstlane(__float_as_int(v)));
}

template <int P> struct Par { static constexpr int v = P; };

// ---------------------------------------------------------------------------
// Kernel 1: fused depthwise branches -> add (bf16).
// Round-7: 8-row half-chunks. xs[4][8][144] + ebuf[8][4][128] => LDS 27 KB
// => 4 blocks/CU (32 waves, occupancy cap) vs 53.8 KB / ~2-3 blocks before.
// Circular-slot math uses rr_eff = 8*(hh&1) + rr which stays ≡ (global row -
// sbase) mod 16, so the verified round-5 accumulator algebra is unchanged.
// Weights in SGPRs (wave-uniform channel), full-width aligned staging.
// ws layout [n][g=c/4][px][c%4] bf16, 8-B px-granules (UNCHANGED).
// ---------------------------------------------------------------------------
__global__ __launch_bounds__(TPB) void k_dw(
    const float* __restrict__ x,
    const float* __restrict__ w0,  const float* __restrict__ b0,
    const float* __restrict__ w01, const float* __restrict__ b01,
    const float* __restrict__ w02, const float* __restrict__ b02,
    const float* __restrict__ w11, const float* __restrict__ b11,
    const float* __restrict__ w12, const float* __restrict__ b12,
    unsigned short* __restrict__ ws)
{
  __shared__ float xs[CHB][8][144];           // 8-row half; px at cols 8..135, pads = 0
  __shared__ unsigned short ebuf[8][CHB][128];
  __shared__ float bias_row[CHB][OROWS];

  const int t = threadIdx.x;
  const int yb = blockIdx.x, g = blockIdx.y, n = blockIdx.z;
  const int ch = t >> 7, xl = t & 127;        // ch uniform per wave
  const int c0 = g * CHB, c = c0 + ch;

  const int obase = yb * OROWS;
  const int oend  = obase + OROWS;
  const int sbase = (obase >= 5) ? (obase - 5) : 0;
  const int lastrow = (oend + 4 <= H_ - 1) ? (oend + 4) : (H_ - 1);
  const int nrows = lastrow - sbase + 1;      // 37 (edge) or 42 (middle)
  const int nhalf = (nrows + 7) >> 3;

  // wave-uniform weights -> SGPRs (41 scalars)
  float w0t[9], w01t[5], w02t[5], w11t[11], w12t[11];
#pragma unroll
  for (int k = 0; k < 9; ++k)  w0t[k] = sgpr(w0[c * 9 + k]);
#pragma unroll
  for (int k = 0; k < 5; ++k)  { w01t[k] = sgpr(w01[c * 5 + k]); w02t[k] = sgpr(w02[c * 5 + k]); }
#pragma unroll
  for (int k = 0; k < 11; ++k) { w11t[k] = sgpr(w11[c * 11 + k]); w12t[k] = sgpr(w12[c * 11 + k]); }

  // boundary-bias table: 4 ch x 32 outputs
  if (t < CHB * OROWS) {
    const int cb = t >> 5, oo = t & 31;
    const int y = obase + oo, cc = c0 + cb;
    float s5 = 0.f, s11 = 0.f;
#pragma unroll
    for (int k = 0; k < 5; ++k)  if ((unsigned)(y - 2 + k) < 128u) s5  += w02[cc * 5 + k];
#pragma unroll
    for (int k = 0; k < 11; ++k) if ((unsigned)(y - 5 + k) < 128u) s11 += w12[cc * 11 + k];
    bias_row[cb][oo] = b0[cc] + b02[cc] + b12[cc] + b01[cc] * s5 + b11[cc] * s11;
  }

  // zero the halo pad columns once (cols 0..7 and 136..143 of all 8 rows)
  if (t < 128) {
    const int zc = t >> 5, zr = (t >> 2) & 7, zq = t & 3;
    const int col = (zq < 2) ? zq * 4 : 136 + (zq - 2) * 4;
    *(float4*)&xs[zc][zr][col] = make_float4(0.f, 0.f, 0.f, 0.f);
  }

  float acc[16];
#pragma unroll
  for (int i = 0; i < 16; ++i) acc[i] = 0.f;

  unsigned short* wsp = ws + (size_t)(n * 32 + g) * HW_ * 4;

  auto stage = [&](int hh) {
    const int rb = 8 * hh;
#pragma unroll
    for (int i = 0; i < 2; ++i) {
      const int id = i * TPB + t;             // 0..1023
      const int chs = id >> 8;                // 0..3
      const int rs  = (id >> 5) & 7;
      const int c4  = id & 31;
      float4 v = make_float4(0.f, 0.f, 0.f, 0.f);
      if (rb + rs < nrows)
        v = *(const float4*)(x + (size_t)((n * C_ + c0 + chs) * H_ + sbase + rb + rs) * W_ + c4 * 4);
      *(float4*)&xs[chs][rs][8 + c4 * 4] = v;
    }
  };

  auto writeout = [&](int hh, int hl) {
    const int rbg = sbase + 8 * hh;
    for (int id = t; id < 1024; id += TPB) {
      const int orr = id >> 7, px = id & 127;
      const int o = rbg + orr - 5;
      if (orr < hl && o >= obase) {
        uint2 pk;
        pk.x = ebuf[orr][0][px] | ((unsigned)ebuf[orr][1][px] << 16);
        pk.y = ebuf[orr][2][px] | ((unsigned)ebuf[orr][3][px] << 16);
        *(uint2*)(wsp + ((size_t)o * W_ + px) * 4) = pk;
      }
    }
  };

  auto compute = [&](auto par, int hh, int hl) {
    constexpr int PAR = decltype(par)::v;     // 0 or 8
    const int rbg = sbase + 8 * hh;
#pragma unroll
    for (int rr = 0; rr < 8; ++rr) {
      if (rr < hl) {
        float win[11];                        // tap k reads px xl-5+k -> col xl+3+k
#pragma unroll
        for (int k = 0; k < 11; ++k) win[k] = xs[ch][rr][xl + 3 + k];
        float h11 = w11t[0] * win[0];
#pragma unroll
        for (int k = 1; k < 11; ++k) h11 += w11t[k] * win[k];
        float h5 = w01t[0] * win[3];
#pragma unroll
        for (int k = 1; k < 5; ++k) h5 += w01t[k] * win[3 + k];
        float r0v = w0t[0] * win[4] + w0t[1] * win[5] + w0t[2] * win[6];
        float r1v = w0t[3] * win[4] + w0t[4] * win[5] + w0t[5] * win[6];
        float r2v = w0t[6] * win[4] + w0t[7] * win[5] + w0t[8] * win[6];
        const int re = PAR + rr;              // ≡ global row - sbase (mod 16)
#pragma unroll
        for (int tt = 0; tt < 11; ++tt) acc[(re + 5 - tt) & 15] += w12t[tt] * h11;
#pragma unroll
        for (int tt = 0; tt < 5; ++tt)  acc[(re + 2 - tt) & 15] += w02t[tt] * h5;
        acc[(re + 1) & 15]  += r0v;
        acc[re & 15]        += r1v;
        acc[(re + 15) & 15] += r2v;
        const int o_e = rbg + rr - 5;         // complete (or warmup garbage: reset only)
        const int slot = (re + 11) & 15;
        if (o_e >= obase)
          ebuf[rr][ch][xl] = (unsigned short)f2bf(acc[slot] + bias_row[ch][o_e - obase]);
        acc[slot] = 0.f;
      }
    }
  };

  stage(0);
  __syncthreads();
  for (int hh = 0; hh < nhalf; ++hh) {
    const int rem = nrows - 8 * hh;
    const int hl = rem < 8 ? rem : 8;
    if (hh & 1) compute(Par<8>{}, hh, hl);
    else        compute(Par<0>{}, hh, hl);
    __syncthreads();                          // ebuf done; xs free
    if (hh + 1 < nhalf) stage(hh + 1);
    writeout(hh, hl);
    __syncthreads();
  }
  // drain outputs 123..127 (bottom y-block only); slot = (o - sbase) & 15
  if (oend == H_) {
#pragma unroll
    for (int orr = 0; orr < 5; ++orr) {
      const int o = H_ - 5 + orr;
      const int slot = (o - sbase) & 15;
      ebuf[orr][ch][xl] = (unsigned short)f2bf(acc[slot] + bias_row[ch][o - obase]);
    }
    __syncthreads();
    for (int id = t; id < 640; id += TPB) {
      const int orr = id >> 7, px = id & 127;
      const int o = H_ - 5 + orr;
      uint2 pk;
      pk.x = ebuf[orr][0][px] | ((unsigned)ebuf[orr][1][px] << 16);
      pk.y = ebuf[orr][2][px] | ((unsigned)ebuf[orr][3][px] << 16);
      *(uint2*)(wsp + ((size_t)o * W_ + px) * 4) = pk;
    }
  }
}

// ---------------------------------------------------------------------------
// Kernel 2: 1x1 channel mix, TRANSPOSED MFMA orientation.
// mfma(A=ws_act, B=w3) -> D[row=px][col=out-ch]. Operand loads are verbatim
// round-5 code with roles swapped (fragment k-convention is symmetric, and
// (W*Act)^T = Act^T * W^T). acc bounces through padded LDS xp[128][66] so the
// epilogue is px-major: each lane owns 4 consecutive px of one channel ->
// x/out are float4, 4 contiguous 256-B segments per instruction (4x fewer
// transactions on the dominant 256 MiB of x+out traffic).
// Block = 512 thr (8 waves x 16 out-ch), 64 px per block, 4096 blocks.
// ---------------------------------------------------------------------------
constexpr int MPX = 64;

__global__ __launch_bounds__(512) void k_mix(
    const float* __restrict__ x,
    const float* __restrict__ w3, const float* __restrict__ b3,
    const unsigned short* __restrict__ ws,
    float* __restrict__ out)
{
  __shared__ float xp[128][66];               // [ch][px] transpose buffer (pad 66)

  const int t = threadIdx.x;
  const int wv = t >> 6, lane = t & 63, q = lane >> 4, lp = lane & 15;
  const int n = blockIdx.y;
  const int pxb = blockIdx.x * MPX;
  const int o0 = wv * 16;                     // this wave's 16 out-channels

  // B fragments = w3: col = out-ch o0+lp, k = ks*32 + q*8 + j (bf16-packed)
  s8v Bw[4];
#pragma unroll
  for (int ks = 0; ks < 4; ++ks) {
    const float* src = w3 + (o0 + lp) * 128 + ks * 32 + q * 8;
    float4 f0 = *(const float4*)src;
    float4 f1 = *(const float4*)(src + 4);
    union { s8v v; unsigned u[4]; } pk;
    pk.u[0] = f2bf(f0.x) | (f2bf(f0.y) << 16);
    pk.u[1] = f2bf(f0.z) | (f2bf(f0.w) << 16);
    pk.u[2] = f2bf(f1.x) | (f2bf(f1.y) << 16);
    pk.u[3] = f2bf(f1.z) | (f2bf(f1.w) << 16);
    Bw[ks] = pk.v;
  }

  const unsigned short* wsn = ws + (size_t)n * 32 * HW_ * 4;

  // 4 subtiles of 16 px: A = activations, row = px (pp), k = cin = ks*32+q*8+j
#pragma unroll
  for (int st = 0; st < 4; ++st) {
    const int pp = pxb + st * 16 + lp;
    s8v Aa[4];
#pragma unroll
    for (int ks = 0; ks < 4; ++ks) {
      const unsigned short* gsrc = wsn + ((size_t)(ks * 8 + 2 * q) * HW_ + pp) * 4;
      union { s8v v; uint2 u2[2]; } pk;
      pk.u2[0] = *(const uint2*)gsrc;                      // cin +0..3
      pk.u2[1] = *(const uint2*)(gsrc + (size_t)HW_ * 4);  // cin +4..7
      Aa[ks] = pk.v;
    }
    f4v acc = {0.f, 0.f, 0.f, 0.f};
#pragma unroll
    for (int ks = 0; ks < 4; ++ks)
      acc = __builtin_amdgcn_mfma_f32_16x16x32_bf16(Aa[ks], Bw[ks], acc, 0, 0, 0);
    // D row = px_local = 4q + r, col = ch = o0+lp -> store into xp
    float2 lo; lo.x = acc[0]; lo.y = acc[1];
    float2 hi; hi.x = acc[2]; hi.y = acc[3];
    *(float2*)&xp[o0 + lp][st * 16 + 4 * q]     = lo;
    *(float2*)&xp[o0 + lp][st * 16 + 4 * q + 2] = hi;
  }
  __syncthreads();

  // px-major epilogue: lane owns 4 consecutive px of one channel
#pragma unroll
  for (int s = 0; s < 4; ++s) {
    const int chv = s * 32 + wv * 4 + q;
    const float b3c = b3[chv];
    float2 p0 = *(const float2*)&xp[chv][lp * 4];
    float2 p1 = *(const float2*)&xp[chv][lp * 4 + 2];
    const size_t base = ((size_t)(n * C_ + chv) << 14) + pxb + lp * 4;
    float4 xv = *(const float4*)(x + base);
    float4 ov;
    ov.x = (p0.x + b3c) * xv.x;
    ov.y = (p0.y + b3c) * xv.y;
    ov.z = (p1.x + b3c) * xv.z;
    ov.w = (p1.y + b3c) * xv.w;
    *(float4*)(out + base) = ov;
  }
}

extern "C" void kernel_launch(void* const* d_in, const int* in_sizes, int n_in,
                              void* d_out, int out_size, void* d_ws, size_t ws_size,
                              hipStream_t stream) {
  const float* x   = (const float*)d_in[0];
  const float* w0  = (const float*)d_in[1];
  const float* b0  = (const float*)d_in[2];
  const float* w01 = (const float*)d_in[3];
  const float* b01 = (const float*)d_in[4];
  const float* w02 = (const float*)d_in[5];
  const float* b02 = (const float*)d_in[6];
  const float* w11 = (const float*)d_in[7];
  const float* b11 = (const float*)d_in[8];
  const float* w12 = (const float*)d_in[9];
  const float* b12 = (const float*)d_in[10];
  const float* w3  = (const float*)d_in[11];
  const float* b3  = (const float*)d_in[12];
  unsigned short* ws = (unsigned short*)d_ws;   // 16*32*16384*4*2 = 64 MiB
  float* out = (float*)d_out;

  dim3 g1(S_, 32, 16);       // (y-splits, 4-ch groups, batch)
  k_dw<<<g1, TPB, 0, stream>>>(x, w0, b0, w01, b01, w02, b02, w11, b11, w12, b12, ws);

  dim3 g2(HW_ / MPX, 16);    // (64-px blocks, batch)
  k_mix<<<g2, 512, 0, stream>>>(x, w3, b3, ws, out);
}

// Round 8
// 363.042 us; speedup vs baseline: 1.0695x; 1.0695x over previous
//
#include <hip/hip_runtime.h>
#include <stdint.h>

using f4v = __attribute__((ext_vector_type(4))) float;
using s8v = __attribute__((ext_vector_type(8))) short;

constexpr int C_ = 128, H_ = 128, W_ = 128, HW_ = H_ * W_;
constexpr int S_ = 4;             // y-splits for k_dw
constexpr int OROWS = H_ / S_;    // 32 output rows per block
constexpr int CHB = 4;            // channels per k_dw block (wave-uniform)
constexpr int TPB = 512;
static_assert(OROWS == 32, "bias table indexing assumes 32 rows/block");

__device__ __forceinline__ unsigned f2bf(float f) {
  union { float f; unsigned u; } v; v.f = f;
  return (v.u + 0x7FFFu + ((v.u >> 16) & 1u)) >> 16;   // RTNE
}

// force a wave-uniform float into an SGPR
__device__ __forceinline__ float sgpr(float v) {
  return __int_as_float(__builtin_amdgcn_readfirstlane(__float_as_int(v)));
}

// ---------------------------------------------------------------------------
// Kernel 1: fused depthwise branches -> add (bf16). BIT-IDENTICAL to the
// round-5/6 verified version (115 us, WRITE == ws payload, VGPR 40).
// Round-7's 8-row half-chunk variant regressed (134 us, occupancy DOWN) and
// is reverted. Block = 512 thr = 4 ch x 128 px; weights in SGPRs.
// ws layout [n][g=c/4][px][c%4] bf16, 8-B px-granules.
// ---------------------------------------------------------------------------
__global__ __launch_bounds__(TPB) void k_dw(
    const float* __restrict__ x,
    const float* __restrict__ w0,  const float* __restrict__ b0,
    const float* __restrict__ w01, const float* __restrict__ b01,
    const float* __restrict__ w02, const float* __restrict__ b02,
    const float* __restrict__ w11, const float* __restrict__ b11,
    const float* __restrict__ w12, const float* __restrict__ b12,
    unsigned short* __restrict__ ws)
{
  __shared__ float xs[CHB][16][144];          // 128 px at cols 8..135; pads = 0
  __shared__ unsigned short ebuf[16][CHB][128];
  __shared__ float bias_row[CHB][OROWS];

  const int t = threadIdx.x;
  const int yb = blockIdx.x, g = blockIdx.y, n = blockIdx.z;
  const int ch = t >> 7, xl = t & 127;        // ch uniform per wave
  const int c0 = g * CHB, c = c0 + ch;

  const int obase = yb * OROWS;
  const int oend  = obase + OROWS;
  const int sbase = (obase >= 5) ? (obase - 5) : 0;
  const int lastrow = (oend + 4 <= H_ - 1) ? (oend + 4) : (H_ - 1);
  const int nrows = lastrow - sbase + 1;      // 37 (edge) or 42 (middle)
  const int nchunk = (nrows + 15) >> 4;

  // wave-uniform weights -> SGPRs (41 scalars)
  float w0t[9], w01t[5], w02t[5], w11t[11], w12t[11];
#pragma unroll
  for (int k = 0; k < 9; ++k)  w0t[k] = sgpr(w0[c * 9 + k]);
#pragma unroll
  for (int k = 0; k < 5; ++k)  { w01t[k] = sgpr(w01[c * 5 + k]); w02t[k] = sgpr(w02[c * 5 + k]); }
#pragma unroll
  for (int k = 0; k < 11; ++k) { w11t[k] = sgpr(w11[c * 11 + k]); w12t[k] = sgpr(w12[c * 11 + k]); }

  // boundary-bias table: 4 ch x 32 outputs
  if (t < CHB * OROWS) {
    const int cb = t >> 5, oo = t & 31;
    const int y = obase + oo, cc = c0 + cb;
    float s5 = 0.f, s11 = 0.f;
#pragma unroll
    for (int k = 0; k < 5; ++k)  if ((unsigned)(y - 2 + k) < 128u) s5  += w02[cc * 5 + k];
#pragma unroll
    for (int k = 0; k < 11; ++k) if ((unsigned)(y - 5 + k) < 128u) s11 += w12[cc * 11 + k];
    bias_row[cb][oo] = b0[cc] + b02[cc] + b12[cc] + b01[cc] * s5 + b11[cc] * s11;
  }

  // zero the halo pad columns once
  if (t < 256) {
    const int zc = t >> 6, zr = (t >> 2) & 15, zq = t & 3;
    const int col = (zq < 2) ? zq * 4 : 136 + (zq - 2) * 4;
    *(float4*)&xs[zc][zr][col] = make_float4(0.f, 0.f, 0.f, 0.f);
  }

  float acc[16];
#pragma unroll
  for (int i = 0; i < 16; ++i) acc[i] = 0.f;

  unsigned short* wsp = ws + (size_t)(n * 32 + g) * HW_ * 4;

  for (int cidx = 0; cidx < nchunk; ++cidx) {
    const int r0g = sbase + cidx * 16;
    const int rem_rows = nrows - cidx * 16;
    const int rlim = rem_rows < 16 ? rem_rows : 16;
    __syncthreads();
#pragma unroll
    for (int i = 0; i < 4; ++i) {
      const int id = i * TPB + t;
      const int chs = id >> 9;
      const int rs  = (id >> 5) & 15;
      const int c4  = id & 31;
      float4 v = make_float4(0.f, 0.f, 0.f, 0.f);
      if (rs < rlim)
        v = *(const float4*)(x + (size_t)((n * C_ + c0 + chs) * H_ + r0g + rs) * W_ + c4 * 4);
      *(float4*)&xs[chs][rs][8 + c4 * 4] = v;
    }
    __syncthreads();
#pragma unroll
    for (int rr = 0; rr < 16; ++rr) {
      if (rr < rlim) {
        float win[11];
#pragma unroll
        for (int k = 0; k < 11; ++k) win[k] = xs[ch][rr][xl + 3 + k];
        float h11 = w11t[0] * win[0];
#pragma unroll
        for (int k = 1; k < 11; ++k) h11 += w11t[k] * win[k];
        float h5 = w01t[0] * win[3];
#pragma unroll
        for (int k = 1; k < 5; ++k) h5 += w01t[k] * win[3 + k];
        float r0v = w0t[0] * win[4] + w0t[1] * win[5] + w0t[2] * win[6];
        float r1v = w0t[3] * win[4] + w0t[4] * win[5] + w0t[5] * win[6];
        float r2v = w0t[6] * win[4] + w0t[7] * win[5] + w0t[8] * win[6];
#pragma unroll
        for (int tt = 0; tt < 11; ++tt) acc[(rr + 5 - tt) & 15] += w12t[tt] * h11;
#pragma unroll
        for (int tt = 0; tt < 5; ++tt)  acc[(rr + 2 - tt) & 15] += w02t[tt] * h5;
        acc[(rr + 1) & 15]  += r0v;
        acc[rr & 15]        += r1v;
        acc[(rr + 15) & 15] += r2v;
        const int o_e = r0g + rr - 5;
        const int slot = (rr + 11) & 15;
        if (o_e >= obase)
          ebuf[rr][ch][xl] = (unsigned short)f2bf(acc[slot] + bias_row[ch][o_e - obase]);
        acc[slot] = 0.f;
      }
    }
    __syncthreads();
    for (int id = t; id < 2048; id += TPB) {
      const int orr = id >> 7, px = id & 127;
      const int o = r0g + orr - 5;
      if (orr < rlim && o >= obase) {
        uint2 pk;
        pk.x = ebuf[orr][0][px] | ((unsigned)ebuf[orr][1][px] << 16);
        pk.y = ebuf[orr][2][px] | ((unsigned)ebuf[orr][3][px] << 16);
        *(uint2*)(wsp + ((size_t)o * W_ + px) * 4) = pk;
      }
    }
  }
  if (oend == H_) {
    __syncthreads();
#pragma unroll
    for (int orr = 0; orr < 5; ++orr) {
      const int o = H_ - 5 + orr;
      const int slot = (o - sbase) & 15;
      ebuf[orr][ch][xl] = (unsigned short)f2bf(acc[slot] + bias_row[ch][o - obase]);
    }
    __syncthreads();
    for (int id = t; id < 640; id += TPB) {
      const int orr = id >> 7, px = id & 127;
      const int o = H_ - 5 + orr;
      uint2 pk;
      pk.x = ebuf[orr][0][px] | ((unsigned)ebuf[orr][1][px] << 16);
      pk.y = ebuf[orr][2][px] | ((unsigned)ebuf[orr][3][px] << 16);
      *(uint2*)(wsp + ((size_t)o * W_ + px) * 4) = pk;
    }
  }
}

// ---------------------------------------------------------------------------
// Kernel 2: 1x1 channel mix via MFMA. BIT-IDENTICAL compute to the round-5
// verified version (total 362 us config). Only change: batch-offset arg n0 so
// the grid can be split into two half-launches (n 0-7, 8-15) — a designed
// experiment to force k_mix dispatches above k_dw's ~115 us into the rocprof
// top-5 IF k_mix is really the ~240 us dominant kernel (H-A). If it stays
// invisible, k_mix < ~115 per half and the residual ~130-150 us of dur_us is
// fixed harness overhead (H-B).
// ---------------------------------------------------------------------------
constexpr int PXB = 64;

__global__ __launch_bounds__(256) void k_mix(
    const float* __restrict__ x,
    const float* __restrict__ w3, const float* __restrict__ b3,
    const unsigned short* __restrict__ ws,
    float* __restrict__ out, int n0)
{
  const int t = threadIdx.x;
  const int wv = t >> 6, lane = t & 63, q = lane >> 4, lp = lane & 15;
  const int n = blockIdx.y + n0;
  const int px0 = blockIdx.x * PXB;

  // A fragments: rows o = 32*wv + 16*m + lp, k-slice ks*32 + q*8 (bf16-packed)
  s8v A[2][4];
  float b3v[2][4];
#pragma unroll
  for (int m = 0; m < 2; ++m) {
    const int o = 32 * wv + 16 * m + lp;
#pragma unroll
    for (int ks = 0; ks < 4; ++ks) {
      const float* src = w3 + o * 128 + ks * 32 + q * 8;
      float4 f0 = *(const float4*)src;
      float4 f1 = *(const float4*)(src + 4);
      union { s8v v; unsigned u[4]; } pk;
      pk.u[0] = f2bf(f0.x) | (f2bf(f0.y) << 16);
      pk.u[1] = f2bf(f0.z) | (f2bf(f0.w) << 16);
      pk.u[2] = f2bf(f1.x) | (f2bf(f1.y) << 16);
      pk.u[3] = f2bf(f1.z) | (f2bf(f1.w) << 16);
      A[m][ks] = pk.v;
    }
#pragma unroll
    for (int r = 0; r < 4; ++r) b3v[m][r] = b3[32 * wv + 16 * m + 4 * q + r];
  }

  const unsigned short* wsn = ws + (size_t)n * 32 * HW_ * 4;

#pragma unroll
  for (int npg = 0; npg < PXB / 16; ++npg) {
    const int pp = px0 + npg * 16 + lp;
    s8v B[4];
#pragma unroll
    for (int ks = 0; ks < 4; ++ks) {
      const int gg8 = ks * 4 + q;            // 8-ch group for k = ks*32+q*8
      const unsigned short* gsrc = wsn + ((size_t)(gg8 * 2) * HW_ + pp) * 4;
      union { s8v v; uint2 u2[2]; } pk;
      pk.u2[0] = *(const uint2*)gsrc;                    // ch 8*gg8+0..3
      pk.u2[1] = *(const uint2*)(gsrc + (size_t)HW_ * 4);// ch 8*gg8+4..7
      B[ks] = pk.v;
    }
    // hoist the x (residual-multiply) loads so they overlap the MFMA chain
    float xv[2][4];
#pragma unroll
    for (int m = 0; m < 2; ++m)
#pragma unroll
      for (int r = 0; r < 4; ++r) {
        const int o = 32 * wv + 16 * m + 4 * q + r;
        xv[m][r] = x[((size_t)(n * C_ + o) << 14) + pp];
      }
    f4v acc[2] = {{0.f,0.f,0.f,0.f},{0.f,0.f,0.f,0.f}};
#pragma unroll
    for (int ks = 0; ks < 4; ++ks) {
#pragma unroll
      for (int m = 0; m < 2; ++m)
        acc[m] = __builtin_amdgcn_mfma_f32_16x16x32_bf16(A[m][ks], B[ks], acc[m], 0, 0, 0);
    }
#pragma unroll
    for (int m = 0; m < 2; ++m)
#pragma unroll
      for (int r = 0; r < 4; ++r) {
        const int o = 32 * wv + 16 * m + 4 * q + r;   // D row = q*4+r
        const size_t idx = ((size_t)(n * C_ + o) << 14) + pp;
        out[idx] = (acc[m][r] + b3v[m][r]) * xv[m][r];
      }
  }
}

extern "C" void kernel_launch(void* const* d_in, const int* in_sizes, int n_in,
                              void* d_out, int out_size, void* d_ws, size_t ws_size,
                              hipStream_t stream) {
  const float* x   = (const float*)d_in[0];
  const float* w0  = (const float*)d_in[1];
  const float* b0  = (const float*)d_in[2];
  const float* w01 = (const float*)d_in[3];
  const float* b01 = (const float*)d_in[4];
  const float* w02 = (const float*)d_in[5];
  const float* b02 = (const float*)d_in[6];
  const float* w11 = (const float*)d_in[7];
  const float* b11 = (const float*)d_in[8];
  const float* w12 = (const float*)d_in[9];
  const float* b12 = (const float*)d_in[10];
  const float* w3  = (const float*)d_in[11];
  const float* b3  = (const float*)d_in[12];
  unsigned short* ws = (unsigned short*)d_ws;   // 16*32*16384*4*2 = 64 MiB
  float* out = (float*)d_out;

  dim3 g1(S_, 32, 16);       // (y-splits, 4-ch groups, batch)
  k_dw<<<g1, TPB, 0, stream>>>(x, w0, b0, w01, b01, w02, b02, w11, b11, w12, b12, ws);

  dim3 g2(HW_ / PXB, 8);     // (64-px blocks, half-batch) x 2 launches
  k_mix<<<g2, 256, 0, stream>>>(x, w3, b3, ws, out, 0);
  k_mix<<<g2, 256, 0, stream>>>(x, w3, b3, ws, out, 8);
}